// Round 1
// baseline (153.594 us; speedup 1.0000x reference)
//
#include <hip/hip_runtime.h>
#include <hip/hip_bf16.h>

// Cross_LocalAttention: windowed attention + LePE depthwise conv.
// B=8, H=W=128, DIM=256, HEADS=8, HD=32, window 8x8 (WS=64).
// One block (256 threads, 4 waves) per (window, head): 16384 blocks.
// Wave w computes rows [16w, 16w+16) of the 64x64 score matrix via
// mfma_f32_16x16x32_bf16 with hi/lo-split q,k for ~fp32 accuracy.

#define SCALE_F 0.17677669529663687f  // 32^-0.5

typedef __attribute__((ext_vector_type(8))) short bf16x8;
typedef __attribute__((ext_vector_type(4))) float f32x4;

static __device__ __forceinline__ unsigned short f2bf(float f) {
    unsigned int u = __builtin_bit_cast(unsigned int, f);
    u += 0x7fffu + ((u >> 16) & 1u);          // RNE
    return (unsigned short)(u >> 16);
}
static __device__ __forceinline__ float bf2f(unsigned short s) {
    unsigned int u = ((unsigned int)s) << 16;
    return __builtin_bit_cast(float, u);
}

__global__ __launch_bounds__(256) void lepe_attn_kernel(
    const float* __restrict__ qkv,
    const float* __restrict__ lw,
    const float* __restrict__ lb,
    float* __restrict__ out)
{
    const int bid  = blockIdx.x;
    const int head = bid & 7;
    const int win  = bid >> 3;
    const int ww   = win & 15;
    const int wh   = (win >> 4) & 15;
    const int b    = win >> 8;
    const int t    = threadIdx.x;

    // LDS. Row strides chosen for 16B alignment of b128 fragment reads and
    // low bank conflict (40 shorts = 80B, 72 shorts = 144B).
    __shared__ __align__(16) short q_hi[64][40];
    __shared__ __align__(16) short q_lo[64][40];
    __shared__ __align__(16) short k_hi[64][40];
    __shared__ __align__(16) short k_lo[64][40];
    __shared__ __align__(16) short v_t[32][72];   // v transposed, perm'd cols
    __shared__ __align__(16) short P_lds[64][72]; // softmax probs (bf16); later
                                                  // aliased as float lepe[64][36]
    __shared__ float w_s[288];  // 32 ch x 9 taps
    __shared__ float b_s[32];

    const float* Qp = qkv;
    const float* Kp = qkv + (size_t)33554432;   // 8*16384*256
    const float* Vp = qkv + (size_t)67108864;
    float* xout = out;
    float* qout = out + (size_t)33554432;

    // per-head depthwise conv weights (contiguous 288 floats) + bias
    for (int i = t; i < 288; i += 256) w_s[i] = lw[head * 288 + i];
    if (t < 32) b_s[t] = lb[head * 32 + t];

    // ---- stage q,k,v: 64 tokens x 32 dims each, float4 per (token, d-quad)
    #pragma unroll
    for (int u = 0; u < 2; ++u) {
        const int idx = t + u * 256;
        const int s   = idx >> 3;      // token in window
        const int d4  = idx & 7;       // which 4-dim quad
        const int row = wh * 8 + (s >> 3);
        const int col = ww * 8 + (s & 7);
        const size_t goff = ((size_t)(b * 16384 + row * 128 + col)) * 256
                          + head * 32 + d4 * 4;

        // Q: scale, emit q-output (exact fp32), hi/lo bf16 into LDS
        float4 fq = *(const float4*)(Qp + goff);
        fq.x *= SCALE_F; fq.y *= SCALE_F; fq.z *= SCALE_F; fq.w *= SCALE_F;
        *(float4*)(qout + ((size_t)bid * 64 + s) * 32 + d4 * 4) = fq;
        {
            unsigned short h0 = f2bf(fq.x), h1 = f2bf(fq.y),
                           h2 = f2bf(fq.z), h3 = f2bf(fq.w);
            unsigned short l0 = f2bf(fq.x - bf2f(h0)), l1 = f2bf(fq.y - bf2f(h1)),
                           l2 = f2bf(fq.z - bf2f(h2)), l3 = f2bf(fq.w - bf2f(h3));
            uint2 hp, lp;
            hp.x = (unsigned)h0 | ((unsigned)h1 << 16);
            hp.y = (unsigned)h2 | ((unsigned)h3 << 16);
            lp.x = (unsigned)l0 | ((unsigned)l1 << 16);
            lp.y = (unsigned)l2 | ((unsigned)l3 << 16);
            *(uint2*)&q_hi[s][d4 * 4] = hp;
            *(uint2*)&q_lo[s][d4 * 4] = lp;
        }
        // K: hi/lo bf16
        {
            float4 fk = *(const float4*)(Kp + goff);
            unsigned short h0 = f2bf(fk.x), h1 = f2bf(fk.y),
                           h2 = f2bf(fk.z), h3 = f2bf(fk.w);
            unsigned short l0 = f2bf(fk.x - bf2f(h0)), l1 = f2bf(fk.y - bf2f(h1)),
                           l2 = f2bf(fk.z - bf2f(h2)), l3 = f2bf(fk.w - bf2f(h3));
            uint2 hp, lp;
            hp.x = (unsigned)h0 | ((unsigned)h1 << 16);
            hp.y = (unsigned)h2 | ((unsigned)h3 << 16);
            lp.x = (unsigned)l0 | ((unsigned)l1 << 16);
            lp.y = (unsigned)l2 | ((unsigned)l3 << 16);
            *(uint2*)&k_hi[s][d4 * 4] = hp;
            *(uint2*)&k_lo[s][d4 * 4] = lp;
        }
        // V: bf16, transposed [d][perm(s)] so PV B-frags are contiguous b128
        {
            float4 fv = *(const float4*)(Vp + goff);
            const int sp = ((s & 15) << 2) | (s >> 4);  // perm(s)
            v_t[d4 * 4 + 0][sp] = (short)f2bf(fv.x);
            v_t[d4 * 4 + 1][sp] = (short)f2bf(fv.y);
            v_t[d4 * 4 + 2][sp] = (short)f2bf(fv.z);
            v_t[d4 * 4 + 3][sp] = (short)f2bf(fv.w);
        }
    }
    __syncthreads();

    const int lane = t & 63;
    const int wid  = t >> 6;
    const int c    = lane & 15;   // mfma col / frag row selector
    const int g    = lane >> 4;   // k-group
    const int i0   = wid * 16;    // this wave's q-row block

    // ---- QK^T (hi/lo split, 3 mfmas per 16x16 tile, K=32 in one shot)
    bf16x8 aqh = *(const bf16x8*)&q_hi[i0 + c][g * 8];
    bf16x8 aql = *(const bf16x8*)&q_lo[i0 + c][g * 8];

    f32x4 sacc[4];
    #pragma unroll
    for (int jt = 0; jt < 4; ++jt) {
        bf16x8 bkh = *(const bf16x8*)&k_hi[jt * 16 + c][g * 8];
        bf16x8 bkl = *(const bf16x8*)&k_lo[jt * 16 + c][g * 8];
        f32x4 acc = {0.f, 0.f, 0.f, 0.f};
        acc = __builtin_amdgcn_mfma_f32_16x16x32_bf16(aqh, bkh, acc, 0, 0, 0);
        acc = __builtin_amdgcn_mfma_f32_16x16x32_bf16(aql, bkh, acc, 0, 0, 0);
        acc = __builtin_amdgcn_mfma_f32_16x16x32_bf16(aqh, bkl, acc, 0, 0, 0);
        sacc[jt] = acc;
    }

    // ---- wave-parallel softmax. Lane holds S[i0+4g+r][16jt+c]; row i lives in
    // the 16 lanes sharing g, so reduce over xor masks 1,2,4,8.
    float mx[4] = {-3.0e38f, -3.0e38f, -3.0e38f, -3.0e38f};
    #pragma unroll
    for (int jt = 0; jt < 4; ++jt)
        #pragma unroll
        for (int r = 0; r < 4; ++r)
            mx[r] = fmaxf(mx[r], sacc[jt][r]);
    #pragma unroll
    for (int r = 0; r < 4; ++r) {
        mx[r] = fmaxf(mx[r], __shfl_xor(mx[r], 1));
        mx[r] = fmaxf(mx[r], __shfl_xor(mx[r], 2));
        mx[r] = fmaxf(mx[r], __shfl_xor(mx[r], 4));
        mx[r] = fmaxf(mx[r], __shfl_xor(mx[r], 8));
    }
    float p[4][4];
    float sm[4] = {0.f, 0.f, 0.f, 0.f};
    #pragma unroll
    for (int jt = 0; jt < 4; ++jt)
        #pragma unroll
        for (int r = 0; r < 4; ++r) {
            p[jt][r] = __expf(sacc[jt][r] - mx[r]);
            sm[r] += p[jt][r];
        }
    #pragma unroll
    for (int r = 0; r < 4; ++r) {
        sm[r] += __shfl_xor(sm[r], 1);
        sm[r] += __shfl_xor(sm[r], 2);
        sm[r] += __shfl_xor(sm[r], 4);
        sm[r] += __shfl_xor(sm[r], 8);
    }
    // normalize, pack lane's 4 cols {c,16+c,32+c,48+c} -> stored cols 4c..4c+3
    // (perm(j) = 4*(j&15) + (j>>4), applied identically to v_t's token axis)
    #pragma unroll
    for (int r = 0; r < 4; ++r) {
        const float inv = 1.0f / sm[r];
        unsigned short b0 = f2bf(p[0][r] * inv);
        unsigned short b1 = f2bf(p[1][r] * inv);
        unsigned short b2 = f2bf(p[2][r] * inv);
        unsigned short b3 = f2bf(p[3][r] * inv);
        uint2 pk;
        pk.x = (unsigned)b0 | ((unsigned)b1 << 16);
        pk.y = (unsigned)b2 | ((unsigned)b3 << 16);
        *(uint2*)&P_lds[i0 + 4 * g + r][4 * c] = pk;
    }
    __syncthreads();

    // ---- PV: O[16 x 32] per wave, K=64 over stored-j index (2 k-steps)
    f32x4 o0 = {0.f, 0.f, 0.f, 0.f};
    f32x4 o1 = {0.f, 0.f, 0.f, 0.f};
    #pragma unroll
    for (int ks = 0; ks < 2; ++ks) {
        bf16x8 pa  = *(const bf16x8*)&P_lds[i0 + c][ks * 32 + g * 8];
        bf16x8 vb0 = *(const bf16x8*)&v_t[c][ks * 32 + g * 8];
        bf16x8 vb1 = *(const bf16x8*)&v_t[16 + c][ks * 32 + g * 8];
        o0 = __builtin_amdgcn_mfma_f32_16x16x32_bf16(pa, vb0, o0, 0, 0, 0);
        o1 = __builtin_amdgcn_mfma_f32_16x16x32_bf16(pa, vb1, o1, 0, 0, 0);
    }
    __syncthreads();  // all waves done reading P_lds before conv overwrites it

    // ---- LePE depthwise 3x3 conv (SAME, per-window zero pad), fp32 accum.
    // Thread (d=t&31, lh=t>>5) computes 8 outputs of row lh for channel d.
    {
        const int td = t & 31;
        const int lh = t >> 5;
        float wv[9];
        #pragma unroll
        for (int k = 0; k < 9; ++k) wv[k] = w_s[td * 9 + k];
        float rv[3][8];
        #pragma unroll
        for (int dy = 0; dy < 3; ++dy) {
            const int r2 = lh + dy - 1;
            #pragma unroll
            for (int x = 0; x < 8; ++x) {
                if (r2 >= 0 && r2 < 8) {
                    const int s  = r2 * 8 + x;
                    const int sp = ((s & 15) << 2) | (s >> 4);
                    rv[dy][x] = bf2f((unsigned short)v_t[td][sp]);
                } else {
                    rv[dy][x] = 0.f;
                }
            }
        }
        float* lepe = (float*)P_lds;  // [64][36] fp32, 9216B == P_lds size
        #pragma unroll
        for (int lwp = 0; lwp < 8; ++lwp) {
            float acc = b_s[td];
            #pragma unroll
            for (int dy = 0; dy < 3; ++dy)
                #pragma unroll
                for (int dx = 0; dx < 3; ++dx) {
                    const int x = lwp + dx - 1;
                    if (x >= 0 && x < 8) acc += wv[dy * 3 + dx] * rv[dy][x];
                }
            lepe[(lh * 8 + lwp) * 36 + td] = acc;
        }
    }
    __syncthreads();

    // ---- epilogue: x = O + lepe, scatter back to [B, H*W, C]
    {
        const float* lepe = (const float*)P_lds;
        #pragma unroll
        for (int r = 0; r < 4; ++r) {
            const int s   = i0 + 4 * g + r;
            const int row = wh * 8 + (s >> 3);
            const int col = ww * 8 + (s & 7);
            float* xo = xout + ((size_t)(b * 16384 + row * 128 + col)) * 256
                      + head * 32;
            xo[c]      = o0[r] + lepe[s * 36 + c];
            xo[16 + c] = o1[r] + lepe[s * 36 + 16 + c];
        }
    }
}

extern "C" void kernel_launch(void* const* d_in, const int* in_sizes, int n_in,
                              void* d_out, int out_size, void* d_ws, size_t ws_size,
                              hipStream_t stream) {
    (void)in_sizes; (void)n_in; (void)out_size; (void)d_ws; (void)ws_size;
    const float* qkv = (const float*)d_in[0];
    const float* lw  = (const float*)d_in[1];
    const float* lb  = (const float*)d_in[2];
    float* out = (float*)d_out;
    lepe_attn_kernel<<<dim3(16384), dim3(256), 0, stream>>>(qkv, lw, lb, out);
}

// Round 2
// 143.693 us; speedup vs baseline: 1.0689x; 1.0689x over previous
//
#include <hip/hip_runtime.h>

// Cross_LocalAttention: windowed attention + LePE depthwise conv.
// B=8, H=W=128, DIM=256, HEADS=8, HD=32, window 8x8 (WS=64).
// One block (256 threads, 4 waves) per (window, head): 16384 blocks.
// Swapped-operand QK^T (mfma(K,Q)) puts a full P-row in each lane; a
// designed V permutation makes the PV A-frag a pure intra-lane repack.
// Single __syncthreads per block; conv fused into the epilogue.

#define SCALE_F 0.17677669529663687f  // 32^-0.5

typedef __attribute__((ext_vector_type(8))) short bf16x8;
typedef __attribute__((ext_vector_type(4))) float f32x4;
typedef __attribute__((ext_vector_type(4))) unsigned int u32x4;

static __device__ __forceinline__ unsigned short f2bf(float f) {  // RNE
    unsigned u = __builtin_bit_cast(unsigned, f);
    u += 0x7fffu + ((u >> 16) & 1u);
    return (unsigned short)(u >> 16);
}
static __device__ __forceinline__ float bf2f(unsigned short s) {
    unsigned u = ((unsigned)s) << 16;
    return __builtin_bit_cast(float, u);
}
// truncation hi/lo split of 2 floats -> packed bf16 dwords (hi exactish+lo)
static __device__ __forceinline__ void split2(float a, float b,
                                              unsigned &hi, unsigned &lo) {
    unsigned ua = __builtin_bit_cast(unsigned, a);
    unsigned ub = __builtin_bit_cast(unsigned, b);
    unsigned ha = ua & 0xffff0000u;
    unsigned hb = ub & 0xffff0000u;
    float ra = a - __builtin_bit_cast(float, ha);
    float rb = b - __builtin_bit_cast(float, hb);
    hi = (ha >> 16) | hb;
    lo = (__builtin_bit_cast(unsigned, ra) >> 16)
       | (__builtin_bit_cast(unsigned, rb) & 0xffff0000u);
}

__global__ __launch_bounds__(256, 5) void lepe_attn_kernel(
    const float* __restrict__ qkv,
    const float* __restrict__ lw,
    const float* __restrict__ lb,
    float* __restrict__ out)
{
    const int bid  = blockIdx.x;
    const int head = bid & 7;
    const int win  = bid >> 3;
    const int ww   = win & 15;
    const int wh   = (win >> 4) & 15;
    const int b    = win >> 8;
    const int t    = threadIdx.x;

    // LDS: 30976 B total -> 5 blocks/CU. Strides keep b128 reads 16B-aligned
    // and at worst 2-way bank-aliased (free).
    __shared__ __align__(16) short q_hi[64][40];
    __shared__ __align__(16) short q_lo[64][40];
    __shared__ __align__(16) short k_hi[64][40];
    __shared__ __align__(16) short k_lo[64][40];
    __shared__ __align__(16) short v_t[32][72];   // V^T, perm'd token axis
    __shared__ __align__(16) short v_lin[64][36]; // V linear, for the conv
    __shared__ float w_s[288];
    __shared__ float b_s[32];

    const float* Qp = qkv;
    const float* Kp = qkv + (size_t)33554432;   // 8*16384*256
    const float* Vp = qkv + (size_t)67108864;
    float* xout = out;
    float* qout = out + (size_t)33554432;

    for (int i = t; i < 288; i += 256) w_s[i] = lw[head * 288 + i];
    if (t < 32) b_s[t] = lb[head * 32 + t];

    // ---- stage q,k,v
    #pragma unroll
    for (int u = 0; u < 2; ++u) {
        const int idx = t + u * 256;
        const int s   = idx >> 3;
        const int d4  = idx & 7;
        const int row = wh * 8 + (s >> 3);
        const int col = ww * 8 + (s & 7);
        const size_t goff = ((size_t)(b * 16384 + row * 128 + col)) * 256
                          + head * 32 + d4 * 4;

        float4 fq = *(const float4*)(Qp + goff);
        float4 fk = *(const float4*)(Kp + goff);
        float4 fv = *(const float4*)(Vp + goff);

        fq.x *= SCALE_F; fq.y *= SCALE_F; fq.z *= SCALE_F; fq.w *= SCALE_F;
        *(float4*)(qout + ((size_t)bid * 64 + s) * 32 + d4 * 4) = fq;

        uint2 hp, lp;
        split2(fq.x, fq.y, hp.x, lp.x);
        split2(fq.z, fq.w, hp.y, lp.y);
        *(uint2*)&q_hi[s][d4 * 4] = hp;
        *(uint2*)&q_lo[s][d4 * 4] = lp;

        split2(fk.x, fk.y, hp.x, lp.x);
        split2(fk.z, fk.w, hp.y, lp.y);
        *(uint2*)&k_hi[s][d4 * 4] = hp;
        *(uint2*)&k_lo[s][d4 * 4] = lp;

        // V: bf16 RNE. Linear copy (conv) + permuted transpose (PV B-frag).
        const unsigned short b0 = f2bf(fv.x), b1 = f2bf(fv.y),
                             b2 = f2bf(fv.z), b3 = f2bf(fv.w);
        uint2 vp;
        vp.x = (unsigned)b0 | ((unsigned)b1 << 16);
        vp.y = (unsigned)b2 | ((unsigned)b3 << 16);
        *(uint2*)&v_lin[s][d4 * 4] = vp;
        const int sp = ((s >> 1) & 1) * 32 + ((s >> 2) & 3) * 8
                     + (s & 1) * 4 + (s >> 4);
        v_t[d4 * 4 + 0][sp] = (short)b0;
        v_t[d4 * 4 + 1][sp] = (short)b1;
        v_t[d4 * 4 + 2][sp] = (short)b2;
        v_t[d4 * 4 + 3][sp] = (short)b3;
    }
    __syncthreads();

    const int lane = t & 63;
    const int wid  = t >> 6;
    const int c    = lane & 15;
    const int g    = lane >> 4;
    const int i0   = wid * 16;

    // ---- QK^T swapped: S[i0+c][16jt+4g+r] in lane(c,g) reg r of tile jt
    const bf16x8 bqh = *(const bf16x8*)&q_hi[i0 + c][g * 8];
    const bf16x8 bql = *(const bf16x8*)&q_lo[i0 + c][g * 8];
    f32x4 sacc[4];
    #pragma unroll
    for (int jt = 0; jt < 4; ++jt) {
        const bf16x8 akh = *(const bf16x8*)&k_hi[jt * 16 + c][g * 8];
        const bf16x8 akl = *(const bf16x8*)&k_lo[jt * 16 + c][g * 8];
        f32x4 acc = {0.f, 0.f, 0.f, 0.f};
        acc = __builtin_amdgcn_mfma_f32_16x16x32_bf16(akh, bqh, acc, 0, 0, 0);
        acc = __builtin_amdgcn_mfma_f32_16x16x32_bf16(akl, bqh, acc, 0, 0, 0);
        acc = __builtin_amdgcn_mfma_f32_16x16x32_bf16(akh, bql, acc, 0, 0, 0);
        sacc[jt] = acc;
    }

    // ---- softmax: row i0+c spread over lanes {c, c+16, c+32, c+48}
    float mx = -3.0e38f;
    #pragma unroll
    for (int jt = 0; jt < 4; ++jt)
        #pragma unroll
        for (int r = 0; r < 4; ++r)
            mx = fmaxf(mx, sacc[jt][r]);
    mx = fmaxf(mx, __shfl_xor(mx, 16));
    mx = fmaxf(mx, __shfl_xor(mx, 32));

    float p[4][4];
    float sm = 0.f;
    #pragma unroll
    for (int jt = 0; jt < 4; ++jt)
        #pragma unroll
        for (int r = 0; r < 4; ++r) {
            p[jt][r] = __expf(sacc[jt][r] - mx);
            sm += p[jt][r];
        }
    sm += __shfl_xor(sm, 16);
    sm += __shfl_xor(sm, 32);
    const float inv = 1.0f / sm;

    // pack P rows to bf16: dwA[r]=(p0,p1), dwB[r]=(p2,p3) at k-col 4g+r(+16jt)
    unsigned dwA[4], dwB[4];
    #pragma unroll
    for (int r = 0; r < 4; ++r) {
        dwA[r] = (unsigned)f2bf(p[0][r] * inv)
               | ((unsigned)f2bf(p[1][r] * inv) << 16);
        dwB[r] = (unsigned)f2bf(p[2][r] * inv)
               | ((unsigned)f2bf(p[3][r] * inv) << 16);
    }
    // A-frags for PV are intra-lane by construction of sp():
    // element e of step ks: P[i0+c][16(e&3)+4g+2ks+(e>>2)]
    const u32x4 w0 = {dwA[0], dwB[0], dwA[1], dwB[1]};
    const u32x4 w1 = {dwA[2], dwB[2], dwA[3], dwB[3]};
    const bf16x8 pa0 = __builtin_bit_cast(bf16x8, w0);
    const bf16x8 pa1 = __builtin_bit_cast(bf16x8, w1);

    // ---- PV
    f32x4 o0 = {0.f, 0.f, 0.f, 0.f};
    f32x4 o1 = {0.f, 0.f, 0.f, 0.f};
    {
        const bf16x8 vb00 = *(const bf16x8*)&v_t[c][g * 8];
        const bf16x8 vb10 = *(const bf16x8*)&v_t[16 + c][g * 8];
        const bf16x8 vb01 = *(const bf16x8*)&v_t[c][32 + g * 8];
        const bf16x8 vb11 = *(const bf16x8*)&v_t[16 + c][32 + g * 8];
        o0 = __builtin_amdgcn_mfma_f32_16x16x32_bf16(pa0, vb00, o0, 0, 0, 0);
        o1 = __builtin_amdgcn_mfma_f32_16x16x32_bf16(pa0, vb10, o1, 0, 0, 0);
        o0 = __builtin_amdgcn_mfma_f32_16x16x32_bf16(pa1, vb01, o0, 0, 0, 0);
        o1 = __builtin_amdgcn_mfma_f32_16x16x32_bf16(pa1, vb11, o1, 0, 0, 0);
    }

    // ---- fused LePE conv + epilogue.
    // Lane's 4 output tokens: s = i0+4g+r -> window row srow, cols scol0+r.
    const int srow  = 2 * wid + (g >> 1);
    const int scol0 = 4 * (g & 1);
    #pragma unroll
    for (int half = 0; half < 2; ++half) {
        const int ch = c + 16 * half;
        float wv[9];
        #pragma unroll
        for (int k2 = 0; k2 < 9; ++k2) wv[k2] = w_s[ch * 9 + k2];
        float patch[3][6];
        #pragma unroll
        for (int dy = 0; dy < 3; ++dy) {
            const int rr  = srow + dy - 1;
            const bool rok = (rr >= 0) && (rr < 8);
            const int rcl = rok ? rr : 0;
            #pragma unroll
            for (int dx = 0; dx < 6; ++dx) {
                const int cc  = scol0 + dx - 1;
                const bool cok = (cc >= 0) && (cc < 8);
                const int ccl = cok ? cc : 0;
                const float vv = bf2f((unsigned short)v_lin[rcl * 8 + ccl][ch]);
                patch[dy][dx] = (rok && cok) ? vv : 0.f;
            }
        }
        const float bb = b_s[ch];
        #pragma unroll
        for (int r = 0; r < 4; ++r) {
            float a = bb;
            #pragma unroll
            for (int dy = 0; dy < 3; ++dy)
                #pragma unroll
                for (int dx = 0; dx < 3; ++dx)
                    a += wv[dy * 3 + dx] * patch[dy][r + dx];
            if (half == 0) o0[r] += a; else o1[r] += a;
        }
    }

    #pragma unroll
    for (int r = 0; r < 4; ++r) {
        const int s   = i0 + 4 * g + r;
        const int row = wh * 8 + (s >> 3);
        const int col = ww * 8 + (s & 7);
        float* xo = xout + ((size_t)(b * 16384 + row * 128 + col)) * 256
                  + head * 32;
        xo[c]      = o0[r];
        xo[16 + c] = o1[r];
    }
}

extern "C" void kernel_launch(void* const* d_in, const int* in_sizes, int n_in,
                              void* d_out, int out_size, void* d_ws, size_t ws_size,
                              hipStream_t stream) {
    (void)in_sizes; (void)n_in; (void)out_size; (void)d_ws; (void)ws_size;
    const float* qkv = (const float*)d_in[0];
    const float* lw  = (const float*)d_in[1];
    const float* lb  = (const float*)d_in[2];
    float* out = (float*)d_out;
    lepe_attn_kernel<<<dim3(16384), dim3(256), 0, stream>>>(qkv, lw, lb, out);
}